// Round 1
// baseline (30.192 us; speedup 1.0000x reference)
//
#include <hip/hip_runtime.h>
#include <math.h>

#define THREADS 256
#define BLOCKS  2048

__device__ __forceinline__ float wave_reduce(float v) {
    #pragma unroll
    for (int off = 32; off > 0; off >>= 1)
        v += __shfl_down(v, off, 64);
    return v;
}

// ---------------- Kernel 1: main streaming reduction ----------------
__global__ __launch_bounds__(THREADS) void loss_main_kernel(
    const float4* __restrict__ pp4,
    const float4* __restrict__ pt4,
    const float4* __restrict__ md4,
    const float4* __restrict__ tg4,
    const float*  __restrict__ Vp,
    float2*       __restrict__ partials,
    int n4)
{
    constexpr float P_ATM    = 0.101325f;
    constexpr float BETA     = 1466.96f;
    constexpr float INV_BETA = 1.0f / 1466.96f;
    constexpr float R_FRAC   = 0.005f / 0.995f;               // air_fraction ratio
    constexpr float C_RP     = R_FRAC * P_ATM;                // r * P_ATM
    constexpr float RHO_MIX  = 851.6f + 1.225f * R_FRAC;      // rho_mix_init
    constexpr float PT_EPS   = 1e-12f;

    const float V = Vp[0];

    float phys = 0.0f;
    float lm   = 0.0f;

    int tid    = blockIdx.x * blockDim.x + threadIdx.x;
    int stride = gridDim.x * blockDim.x;

    for (int i = tid; i < n4; i += stride) {
        float4 a = pp4[i];
        float4 b = pt4[i];
        float4 c = md4[i];
        float4 d = tg4[i];
        const float* pa = (const float*)&a;
        const float* pb = (const float*)&b;
        const float* pc = (const float*)&c;
        const float* pd = (const float*)&d;
        #pragma unroll
        for (int j = 0; j < 4; ++j) {
            float pp = pa[j];
            float pt = pb[j];
            float md = pc[j];
            float tg = pd[j];

            // drho_mix_dp(pp * 0.1), POLYTROPIC_INDEX == 1
            float p_used  = fmaxf(pp * 0.1f, 1.0f);           // P_MIN = 1.0
            float inv_pu  = __builtin_amdgcn_rcpf(p_used);
            float p_denom = C_RP * inv_pu;                    // r * P_ATM / p_used
            float p_ratio = p_denom * inv_pu;                 // p_denom / p_used
            float e       = __expf((P_ATM - p_used) * INV_BETA) * INV_BETA;
            float denom   = BETA * e + p_denom;
            float inv_d   = __builtin_amdgcn_rcpf(denom);
            float drho    = RHO_MIX * (e + p_ratio) * inv_d * inv_d;

            float res  = V * drho * pt - md;
            bool  m    = fabsf(pt) >= PT_EPS;
            phys += m ? fabsf(res)      : 0.0f;
            lm   += m ? fabsf(tg - pp)  : 0.0f;
        }
    }

    // block reduce: wave shuffle, then LDS across the 4 waves
    phys = wave_reduce(phys);
    lm   = wave_reduce(lm);

    __shared__ float sp[4];
    __shared__ float sl[4];
    int lane = threadIdx.x & 63;
    int w    = threadIdx.x >> 6;
    if (lane == 0) { sp[w] = phys; sl[w] = lm; }
    __syncthreads();
    if (threadIdx.x == 0) {
        float P = sp[0] + sp[1] + sp[2] + sp[3];
        float L = sl[0] + sl[1] + sl[2] + sl[3];
        partials[blockIdx.x] = make_float2(P, L);
    }
}

// ---------------- Kernel 2: final reduce + BCE + compose ----------------
__global__ __launch_bounds__(THREADS) void loss_finish_kernel(
    const float2* __restrict__ partials, int nblk,
    const float*  __restrict__ logit,     // fault_logit (B,1) flat
    const float*  __restrict__ yf,        // targets_fault (B,)
    int nb,
    float*        __restrict__ out,
    float inv_ns)                          // 1/(b*s)
{
    float phys = 0.0f, lm = 0.0f, cls = 0.0f;

    for (int i = threadIdx.x; i < nblk; i += THREADS) {
        float2 p = partials[i];
        phys += p.x;
        lm   += p.y;
    }
    for (int i = threadIdx.x; i < nb; i += THREADS) {
        float x = logit[i];
        float y = yf[i];
        cls += fmaxf(x, 0.0f) - x * y + log1pf(__expf(-fabsf(x)));
    }

    phys = wave_reduce(phys);
    lm   = wave_reduce(lm);
    cls  = wave_reduce(cls);

    __shared__ float sp[4], sl[4], sc[4];
    int lane = threadIdx.x & 63;
    int w    = threadIdx.x >> 6;
    if (lane == 0) { sp[w] = phys; sl[w] = lm; sc[w] = cls; }
    __syncthreads();
    if (threadIdx.x == 0) {
        float P = sp[0] + sp[1] + sp[2] + sp[3];
        float L = sl[0] + sl[1] + sl[2] + sl[3];
        float C = sc[0] + sc[1] + sc[2] + sc[3];

        float loss_physics = P * inv_ns;
        float loss_M       = L * inv_ns;
        float loss_cls     = C * (1.0f / 512.0f) * ((float)512 / (float)nb) * ((float)nb / 512.0f); // = C/nb
        loss_cls = C / (float)nb;

        out[0] = loss_M + 0.5f * loss_physics + 0.5f * loss_cls;  // total
        out[1] = loss_M;
        out[2] = loss_physics;
        out[3] = loss_cls;
    }
}

extern "C" void kernel_launch(void* const* d_in, const int* in_sizes, int n_in,
                              void* d_out, int out_size, void* d_ws, size_t ws_size,
                              hipStream_t stream) {
    // inputs (setup_inputs order):
    // 0: p_pred (B,S,1) f32   1: p_t_pred (B,S,1) f32   2: fault_logit (B,1) f32
    // 3: targets_fault (B,) f32   4: mdot_A (B,S) f32   5: targets_p_orig (B,S,1) f32
    // 6: V (1,) f32
    const float* p_pred   = (const float*)d_in[0];
    const float* p_t_pred = (const float*)d_in[1];
    const float* logit    = (const float*)d_in[2];
    const float* yfault   = (const float*)d_in[3];
    const float* mdot_A   = (const float*)d_in[4];
    const float* tgt_p    = (const float*)d_in[5];
    const float* V        = (const float*)d_in[6];

    int n  = in_sizes[0];       // B*S = 8388608 (divisible by 4)
    int nb = in_sizes[3];       // B = 512
    int n4 = n / 4;

    float2* partials = (float2*)d_ws;   // BLOCKS float2 = 16 KB

    loss_main_kernel<<<BLOCKS, THREADS, 0, stream>>>(
        (const float4*)p_pred, (const float4*)p_t_pred,
        (const float4*)mdot_A, (const float4*)tgt_p,
        V, partials, n4);

    loss_finish_kernel<<<1, THREADS, 0, stream>>>(
        partials, BLOCKS, logit, yfault, nb,
        (float*)d_out, 1.0f / (float)n);
}